// Round 1
// baseline (243.701 us; speedup 1.0000x reference)
//
#include <hip/hip_runtime.h>

// MultiScaleRoIAlign: B=2, Nb=256 (R=512 rois), C=256, PH=PW=7, GRID=2.
// Levels: feat0 200x200 s=0.25, feat1 100x100 s=0.125, feat2 50x50 s=0.0625,
// feat3 25x25 s=0.03125. Output [R, C, 7, 7] float32.

#define PHW 49          // 7*7 bins
#define NSAMP 196       // 49 bins * 4 grid samples

__global__ __launch_bounds__(256) void msroi_kernel(
    const float* __restrict__ f0, const float* __restrict__ f1,
    const float* __restrict__ f2, const float* __restrict__ f3,
    const float* __restrict__ boxes, float* __restrict__ out)
{
    const int C = 256, Nb = 256;
    const int r = blockIdx.x;           // roi index, 0..511
    const int b = r / Nb;               // batch index
    const int tid = threadIdx.x;

    // ---- per-roi params (wave-uniform, every thread recomputes) ----
    const float x1b = boxes[r * 4 + 0];
    const float y1b = boxes[r * 4 + 1];
    const float x2b = boxes[r * 4 + 2];
    const float y2b = boxes[r * 4 + 3];
    const float area = fmaxf((x2b - x1b) * (y2b - y1b), 0.0f);
    const float s = sqrtf(area);
    float lv = floorf(4.0f + log2f(s / 224.0f + 1e-6f));
    lv = fminf(fmaxf(lv, 2.0f), 5.0f);
    const int lvl = (int)lv - 2;        // 0..3

    const float* feat;
    int H, W;
    float scale;
    switch (lvl) {
        case 0:  feat = f0; H = 200; W = 200; scale = 0.25f;    break;
        case 1:  feat = f1; H = 100; W = 100; scale = 0.125f;   break;
        case 2:  feat = f2; H = 50;  W = 50;  scale = 0.0625f;  break;
        default: feat = f3; H = 25;  W = 25;  scale = 0.03125f; break;
    }

    const float x1 = x1b * scale, y1 = y1b * scale;
    const float x2 = x2b * scale, y2 = y2b * scale;
    const float roi_w = fmaxf(x2 - x1, 1.0f);
    const float roi_h = fmaxf(y2 - y1, 1.0f);
    const float bin_w = roi_w * (1.0f / 7.0f);
    const float bin_h = roi_h * (1.0f / 7.0f);

    // ---- phase 1: 196 sample points -> LDS (corner offsets + weights) ----
    // weights carry the 1/4 grid-mean factor and the validity mask.
    __shared__ int4   s_off[NSAMP];   // plane-relative offsets: ll, lh, hl, hh
    __shared__ float4 s_wt[NSAMP];

    if (tid < NSAMP) {
        const int samp = tid;          // samp = bin*4 + g, g = iy*2+ix
        const int bin = samp >> 2;
        const int g   = samp & 3;
        const int ph = bin / 7;
        const int pw = bin - ph * 7;
        const int iy = g >> 1, ix = g & 1;
        const float gy = (float)ph + ((float)iy + 0.5f) * 0.5f;
        const float gx = (float)pw + ((float)ix + 0.5f) * 0.5f;
        const float y = y1 + gy * bin_h;
        const float x = x1 + gx * bin_w;
        const bool valid = (y >= -1.0f) && (y <= (float)H) &&
                           (x >= -1.0f) && (x <= (float)W);
        const float yc = fminf(fmaxf(y, 0.0f), (float)(H - 1));
        const float xc = fminf(fmaxf(x, 0.0f), (float)(W - 1));
        const int yl = (int)floorf(yc);
        const int xl = (int)floorf(xc);
        const int yh = min(yl + 1, H - 1);
        const int xh = min(xl + 1, W - 1);
        const float ly = yc - (float)yl;
        const float lx = xc - (float)xl;
        const float hy = 1.0f - ly, hx = 1.0f - lx;
        const float m = valid ? 0.25f : 0.0f;
        s_off[samp] = make_int4(yl * W + xl, yl * W + xh, yh * W + xl, yh * W + xh);
        s_wt[samp]  = make_float4(hy * hx * m, hy * lx * m, ly * hx * m, ly * lx * m);
    }
    __syncthreads();

    // ---- phase 2: 256 ch x 49 bins = 12544 outputs, 49 iters x 256 threads.
    // idx = it*256 + tid; c = idx/49, bin = idx%49 -> coalesced stores.
    const int planeBase = b * C;
    const size_t outBase = (size_t)r * C * PHW;
    for (int it = 0; it < PHW; ++it) {
        const int idx = it * 256 + tid;
        const int c = idx / PHW;
        const int bin = idx - c * PHW;
        const float* __restrict__ fp = feat + (size_t)(planeBase + c) * (H * W);
        float acc = 0.0f;
#pragma unroll
        for (int g = 0; g < 4; ++g) {
            const int samp = bin * 4 + g;
            const int4   o = s_off[samp];
            const float4 w = s_wt[samp];
            acc += w.x * fp[o.x] + w.y * fp[o.y] + w.z * fp[o.z] + w.w * fp[o.w];
        }
        out[outBase + idx] = acc;
    }
}

extern "C" void kernel_launch(void* const* d_in, const int* in_sizes, int n_in,
                              void* d_out, int out_size, void* d_ws, size_t ws_size,
                              hipStream_t stream) {
    const float* f0 = (const float*)d_in[0];
    const float* f1 = (const float*)d_in[1];
    const float* f2 = (const float*)d_in[2];
    const float* f3 = (const float*)d_in[3];
    const float* boxes = (const float*)d_in[4];
    float* out = (float*)d_out;

    const int R = in_sizes[4] / 4;   // 512 rois
    msroi_kernel<<<R, 256, 0, stream>>>(f0, f1, f2, f3, boxes, out);
}